// Round 5
// baseline (951.543 us; speedup 1.0000x reference)
//
#include <hip/hip_runtime.h>
#include <hip/hip_bf16.h>

// Problem dims
#define B_  32
#define C_  16
#define Hh  64
#define Ww  64
#define O_  256
#define Kk  5
#define Ho_ 60
#define Wo_ 60
#define Dd  400                 // C*K*K
#define Nn  (B_*Ho_*Wo_)        // 115200
#define NY  ((size_t)B_*O_*Ho_*Wo_)  // 29491200

typedef float f4 __attribute__((ext_vector_type(4)));

// ---------------- prep: w [O][D] -> wT4 [D][64 lanes][4 u], zero counts ----------------
// wT4[k*256 + lane*4 + u] = w[lane + 64u][k]  -> bb load is one ds_read_b128 per (k, lane)
__global__ void prep_kernel(const float* __restrict__ w, float* __restrict__ wT4,
                            int* __restrict__ count) {
    int k = blockIdx.x;              // 0..399
    int o = threadIdx.x;             // 0..255
    wT4[k * O_ + (o & 63) * 4 + (o >> 6)] = w[o * Dd + k];
    if (blockIdx.x == 0) count[o] = 0;
}

// ---------------- phase 1: fp32 conv (2 output rows/block) + argmax + winner append ------
// grid = 32*30 blocks (b, ho pair), 256 threads.
// lane txo owns o = txo + 64u; wave ty owns wo in [16*ty, 16*ty+16); rows ho, ho+1.
__launch_bounds__(256, 2)
__global__ void conv_argmax_kernel(const float* __restrict__ x, const float* __restrict__ wT4,
                                   float* __restrict__ y, int* __restrict__ count,
                                   int* __restrict__ lw_n, float* __restrict__ lw_s,
                                   int cap) {
    __shared__ float xs[C_][6][68];      // 26,112 B : x rows ho..ho+5 per channel (+pad)
    __shared__ float wsb[2][25 * O_];    // 51,200 B : double-buffered wT4 chunk

    const int tid = threadIdx.x;
    const int txo = tid & 63;
    const int ty  = tid >> 6;            // wave id 0..3
    const int b   = blockIdx.x / 30;
    const int ho  = (blockIdx.x % 30) * 2;
    const int wo0 = ty * 16;

    // ---- issue async stage of weight chunk 0 ASAP (hidden under xs staging)
    {
        const float* src = wT4;          // chunk 0
        #pragma unroll
        for (int t = 0; t < 7; ++t) {
            int k = ty + 4 * t;          // wave-uniform
            if (k < 25) {
                const float* g = src + k * O_ + txo * 4;     // per-lane 16B
                __builtin_amdgcn_global_load_lds(
                    (const __attribute__((address_space(1))) void*)g,
                    (__attribute__((address_space(3))) void*)&wsb[0][k * O_], 16, 0, 0);
            }
        }
    }

    // ---- stage x patch: 96 rows (c=0..15, i=0..5) of 64 floats, + zero pad cols 64..67
    {
        const float* xb = x + (size_t)b * (C_ * Hh * Ww);
        #pragma unroll
        for (int s = 0; s < 6; ++s) {
            int idx = tid + s * 256;      // 0..1535
            int row  = idx >> 4;          // 0..95
            int col4 = idx & 15;
            int c = row / 6, i = row - (row / 6) * 6;
            const f4* srcp = reinterpret_cast<const f4*>(xb + (c * Hh + (ho + i)) * Ww) + col4;
            *reinterpret_cast<f4*>(&xs[c][i][col4 * 4]) = *srcp;
        }
        if (tid < 96) {
            int c = tid / 6, i = tid - (tid / 6) * 6;
            f4 z = {0.f, 0.f, 0.f, 0.f};
            *reinterpret_cast<f4*>(&xs[c][i][64]) = z;
        }
    }

    float accA[16][4], accB[16][4];      // rows ho, ho+1
    #pragma unroll
    for (int r = 0; r < 16; ++r) {
        #pragma unroll
        for (int u = 0; u < 4; ++u) { accA[r][u] = 0.f; accB[r][u] = 0.f; }
    }

    asm volatile("s_waitcnt vmcnt(0)" ::: "memory");   // chunk 0 + xs loads arrived
    __syncthreads();

    // ---- main loop: one barrier per chunk; stage c+1 while computing c
    #pragma unroll 1
    for (int c = 0; c < C_; ++c) {
        const int cur = c & 1;
        if (c + 1 < C_) {
            const float* src = wT4 + (c + 1) * 25 * O_;
            #pragma unroll
            for (int t = 0; t < 7; ++t) {
                int k = ty + 4 * t;
                if (k < 25) {
                    const float* g = src + k * O_ + txo * 4;
                    __builtin_amdgcn_global_load_lds(
                        (const __attribute__((address_space(1))) void*)g,
                        (__attribute__((address_space(3))) void*)&wsb[cur ^ 1][k * O_], 16, 0, 0);
                }
            }
        }
        const float* wsc = &wsb[cur][0];

        #pragma unroll 1
        for (int i = 0; i < 6; ++i) {
            float seg[20];               // xs[c][i][wo0 .. wo0+19] (wave-uniform broadcast)
            #pragma unroll
            for (int t = 0; t < 5; ++t) {
                f4 v = *reinterpret_cast<const f4*>(&xs[c][i][wo0 + 4 * t]);
                seg[4*t+0] = v.x; seg[4*t+1] = v.y; seg[4*t+2] = v.z; seg[4*t+3] = v.w;
            }
            if (i < 5) {                 // contributes to row ho with tap i
                #pragma unroll
                for (int j = 0; j < 5; ++j) {
                    f4 bb = *reinterpret_cast<const f4*>(wsc + (i * 5 + j) * O_ + txo * 4);
                    #pragma unroll
                    for (int r = 0; r < 16; ++r) {
                        const float a = seg[r + j];
                        accA[r][0] = fmaf(a, bb.x, accA[r][0]);
                        accA[r][1] = fmaf(a, bb.y, accA[r][1]);
                        accA[r][2] = fmaf(a, bb.z, accA[r][2]);
                        accA[r][3] = fmaf(a, bb.w, accA[r][3]);
                    }
                }
            }
            if (i >= 1) {                // contributes to row ho+1 with tap i-1
                #pragma unroll
                for (int j = 0; j < 5; ++j) {
                    f4 bb = *reinterpret_cast<const f4*>(wsc + ((i - 1) * 5 + j) * O_ + txo * 4);
                    #pragma unroll
                    for (int r = 0; r < 16; ++r) {
                        const float a = seg[r + j];
                        accB[r][0] = fmaf(a, bb.x, accB[r][0]);
                        accB[r][1] = fmaf(a, bb.y, accB[r][1]);
                        accB[r][2] = fmaf(a, bb.z, accB[r][2]);
                        accB[r][3] = fmaf(a, bb.w, accB[r][3]);
                    }
                }
            }
        }

        asm volatile("s_waitcnt vmcnt(0)" ::: "memory");   // chunk c+1 arrived
        __syncthreads();
    }

    // ---- epilogue: per-row argmax (exact ties), winner append, fp32 y stores
    auto finish = [&](float (&acc)[16][4], int rr) {
        #pragma unroll
        for (int r = 0; r < 16; ++r) {
            const int wo = wo0 + r;
            float v = fmaxf(fmaxf(acc[r][0], acc[r][1]), fmaxf(acc[r][2], acc[r][3]));
            #pragma unroll
            for (int off = 32; off >= 1; off >>= 1) v = fmaxf(v, __shfl_xor(v, off));
            if (wo < Wo_) {
                const int n = (b * Ho_ + ho + rr) * Wo_ + wo;
                #pragma unroll
                for (int u = 0; u < 4; ++u) {
                    if (acc[r][u] == v) {            // winner (possibly tied)
                        const int o = txo + 64 * u;
                        int pos = atomicAdd(&count[o], 1);
                        if (pos < cap) { lw_n[o * cap + pos] = n; lw_s[o * cap + pos] = v; }
                    }
                }
            }
        }
        const int nf4 = (wo0 == 48) ? 3 : 4;
        #pragma unroll
        for (int u = 0; u < 4; ++u) {
            const int o = txo + 64 * u;
            float* row = y + ((size_t)(b * O_ + o) * Ho_ + (ho + rr)) * (size_t)Wo_ + wo0;
            #pragma unroll
            for (int q = 0; q < 4; ++q) {
                if (q < nf4) {
                    f4 v4 = { acc[q * 4 + 0][u], acc[q * 4 + 1][u],
                              acc[q * 4 + 2][u], acc[q * 4 + 3][u] };
                    *reinterpret_cast<f4*>(row + q * 4) = v4;
                }
            }
        }
    };
    finish(accA, 0);
    finish(accB, 1);
}

// ---------------- phase 2a: per-slice partial sums (4 slices per o) ----------------
__global__ void delta_part_kernel(const float* __restrict__ x,
                                  const int* __restrict__ count, const int* __restrict__ lw_n,
                                  const float* __restrict__ lw_s, float* __restrict__ partial,
                                  float* __restrict__ ssum_part, int cap) {
    const int o   = blockIdx.x >> 2;
    const int sl  = blockIdx.x & 3;
    const int tid = threadIdx.x;
    int cnt = count[o]; if (cnt > cap) cnt = cap;
    const int e0 = (cnt * sl) >> 2;
    const int e1 = (cnt * (sl + 1)) >> 2;

    const int d0 = tid;
    const int c0 = d0 / 25, r0 = d0 % 25, i0 = r0 / 5, j0 = r0 % 5;
    const bool has1 = (tid < Dd - 256);
    const int dd1 = has1 ? tid + 256 : 0;
    const int c1 = dd1 / 25, r1 = dd1 % 25, i1 = r1 / 5, j1 = r1 % 5;

    const int* ln = lw_n + (size_t)o * cap;
    const float* ls = lw_s + (size_t)o * cap;

    float acc0 = 0.f, acc1 = 0.f, ssum = 0.f;
    for (int e = e0; e < e1; ++e) {
        const int n = ln[e];
        const float s = ls[e];
        const int bb = n / 3600;
        const int rem = n - bb * 3600;
        const int hh = rem / 60;
        const int ww2 = rem - hh * 60;
        ssum += s;
        const float* xb = x + (size_t)bb * (C_ * Hh * Ww);
        acc0 += s * xb[(c0 * Hh + hh + i0) * Ww + ww2 + j0];
        if (has1) acc1 += s * xb[(c1 * Hh + hh + i1) * Ww + ww2 + j1];
    }
    float* pp = partial + ((size_t)o * 4 + sl) * Dd;
    pp[tid] = acc0;
    if (has1) pp[tid + 256] = acc1;
    if (tid == 0) ssum_part[o * 4 + sl] = ssum;
}

// ---------------- phase 2b: reduce partials, apply -ssum/N * w ----------------
__global__ void delta_reduce_kernel(const float* __restrict__ w, const float* __restrict__ partial,
                                    const float* __restrict__ ssum_part,
                                    float* __restrict__ dout) {
    const int o = blockIdx.x, tid = threadIdx.x;
    const float ssum = ssum_part[o * 4] + ssum_part[o * 4 + 1]
                     + ssum_part[o * 4 + 2] + ssum_part[o * 4 + 3];
    const float invN = 1.0f / (float)Nn;
    const float* pp = partial + (size_t)o * 4 * Dd;
    float a0 = pp[tid] + pp[Dd + tid] + pp[2 * Dd + tid] + pp[3 * Dd + tid];
    dout[NY + (size_t)o * Dd + tid] = a0 * invN - ssum * invN * w[o * Dd + tid];
    if (tid < Dd - 256) {
        const int t2 = tid + 256;
        float a1 = pp[t2] + pp[Dd + t2] + pp[2 * Dd + t2] + pp[3 * Dd + t2];
        dout[NY + (size_t)o * Dd + t2] = a1 * invN - ssum * invN * w[o * Dd + t2];
    }
}

extern "C" void kernel_launch(void* const* d_in, const int* in_sizes, int n_in,
                              void* d_out, int out_size, void* d_ws, size_t ws_size,
                              hipStream_t stream) {
    (void)in_sizes; (void)n_in; (void)out_size;
    const float* x = (const float*)d_in[0];
    const float* w = (const float*)d_in[1];
    float* out = (float*)d_out;

    char* ws = (char*)d_ws;
    int*   count     = (int*)ws;                                   // 1,024 B
    float* wT4       = (float*)(ws + 1024);                        // 409,600 B
    float* partial   = (float*)(ws + 410624);                      // 256*4*400*4 = 1,638,400 B
    float* ssum_part = (float*)(ws + 410624 + 1638400);            // 4,096 B
    const size_t base = 410624 + 1638400 + 4096;                   // 2,053,120 B

    // size winner lists from the actual workspace; never write beyond it
    size_t avail = (ws_size > base) ? (ws_size - base) : 0;
    long long cap_ll = (long long)(avail / ((size_t)O_ * 8));
    int cap = (int)(cap_ll > 4096 ? 4096 : (cap_ll < 1 ? 1 : cap_ll));

    int*   lw_n = (int*)(ws + base);
    float* lw_s = (float*)(ws + base + (size_t)O_ * cap * 4);

    prep_kernel<<<dim3(Dd), dim3(O_), 0, stream>>>(w, wT4, count);
    conv_argmax_kernel<<<dim3(B_ * 30), dim3(256), 0, stream>>>(x, wT4, out, count, lw_n, lw_s, cap);
    delta_part_kernel<<<dim3(O_ * 4), dim3(256), 0, stream>>>(x, count, lw_n, lw_s, partial, ssum_part, cap);
    delta_reduce_kernel<<<dim3(O_), dim3(256), 0, stream>>>(w, partial, ssum_part, out);
}

// Round 6
// 376.674 us; speedup vs baseline: 2.5262x; 2.5262x over previous
//
#include <hip/hip_runtime.h>
#include <hip/hip_bf16.h>

// Problem dims
#define B_  32
#define C_  16
#define Hh  64
#define Ww  64
#define O_  256
#define Kk  5
#define Ho_ 60
#define Wo_ 60
#define Dd  400                 // C*K*K
#define Nn  (B_*Ho_*Wo_)        // 115200
#define NY  ((size_t)B_*O_*Ho_*Wo_)  // 29491200

typedef float f4 __attribute__((ext_vector_type(4)));

// ---------------- prep: w [O][D] -> wT4 [D][64 lanes][4 u], zero counts ----------------
// wT4[k*256 + lane*4 + u] = w[lane + 64u][k]  -> per-(k,lane) weight read is one 16B load
__global__ void prep_kernel(const float* __restrict__ w, float* __restrict__ wT4,
                            int* __restrict__ count) {
    int k = blockIdx.x;              // 0..399
    int o = threadIdx.x;             // 0..255
    wT4[k * O_ + (o & 63) * 4 + (o >> 6)] = w[o * Dd + k];
    if (blockIdx.x == 0) count[o] = 0;
}

// ---------------- phase 1: fp32 conv + argmax + winner append + fp32 y ----------------
// grid = 32*60 blocks (one per (b,ho)), 256 threads.
// lane txo owns o = txo + 64u (u=0..3); wave ty owns wo in [16*ty, 16*ty+16).
// Weights are NOT staged in LDS: each lane streams its own 16B slice of wT4 from L2,
// software-pipelined one (c,i)-group ahead in registers. Zero barriers in the K-loop.
__launch_bounds__(256, 3)
__global__ void conv_argmax_kernel(const float* __restrict__ x, const float* __restrict__ wT4,
                                   float* __restrict__ y, int* __restrict__ count,
                                   int* __restrict__ lw_n, float* __restrict__ lw_s,
                                   int cap) {
    __shared__ float xs[C_ * Kk][68];    // 21,760 B : 80 x-rows (g = c*5+i), cols 0..63 + pad

    const int tid = threadIdx.x;
    const int txo = tid & 63;
    const int ty  = tid >> 6;            // wave id 0..3
    const int b   = blockIdx.x / Ho_;
    const int ho  = blockIdx.x % Ho_;
    const int wo0 = ty * 16;

    // ---- stage x patch: rows g=0..79 (c=g/5, i=g%5), 64 floats each + zero pad
    {
        const float* xb = x + (size_t)b * (C_ * Hh * Ww);
        #pragma unroll
        for (int s = 0; s < 5; ++s) {
            int idx = tid + s * 256;      // 0..1279
            int row  = idx >> 4;          // 0..79
            int col4 = idx & 15;
            int c = row / 5, i = row - (row / 5) * 5;
            const f4* srcp = reinterpret_cast<const f4*>(xb + (c * Hh + (ho + i)) * Ww) + col4;
            *reinterpret_cast<f4*>(&xs[row][col4 * 4]) = *srcp;
        }
        if (tid < 80) {
            f4 z = {0.f, 0.f, 0.f, 0.f};
            *reinterpret_cast<f4*>(&xs[tid][64]) = z;
        }
    }

    float acc[16][4];
    #pragma unroll
    for (int r = 0; r < 16; ++r) {
        acc[r][0] = 0.f; acc[r][1] = 0.f; acc[r][2] = 0.f; acc[r][3] = 0.f;
    }

    __syncthreads();                     // xs ready; no further barriers until epilogue

    // per-lane weight stream base: group g covers wT4[(g*5+j)*256 + txo*4], j=0..4
    const float* wp = wT4 + txo * 4;

    // one (c,i)-group: 5 weight f4s (already in regs) x 20-float seg -> 320 FMAs
    auto compute = [&](const f4 (&wb)[5], int g) {
        const float* xrow = &xs[g][wo0];
        float seg[20];
        #pragma unroll
        for (int t = 0; t < 5; ++t) {
            f4 v = *reinterpret_cast<const f4*>(xrow + 4 * t);
            seg[4*t+0] = v.x; seg[4*t+1] = v.y; seg[4*t+2] = v.z; seg[4*t+3] = v.w;
        }
        #pragma unroll
        for (int j = 0; j < 5; ++j) {
            #pragma unroll
            for (int r = 0; r < 16; ++r) {
                const float a = seg[r + j];
                acc[r][0] = fmaf(a, wb[j].x, acc[r][0]);
                acc[r][1] = fmaf(a, wb[j].y, acc[r][1]);
                acc[r][2] = fmaf(a, wb[j].z, acc[r][2]);
                acc[r][3] = fmaf(a, wb[j].w, acc[r][3]);
            }
        }
    };

    // software pipeline: named A/B register buffers, loads one group ahead
    f4 wbA[5], wbB[5];
    #pragma unroll
    for (int j = 0; j < 5; ++j)
        wbA[j] = *reinterpret_cast<const f4*>(wp + (size_t)j * O_);

    #pragma unroll 1
    for (int g = 0; g < 80; g += 2) {
        {   // prefetch group g+1 into B
            const float* wn = wp + (size_t)(g + 1) * 5 * O_;
            #pragma unroll
            for (int j = 0; j < 5; ++j)
                wbB[j] = *reinterpret_cast<const f4*>(wn + (size_t)j * O_);
        }
        compute(wbA, g);
        {   // prefetch group g+2 into A (clamped dup-load on last iter)
            const int gn = (g + 2 < 80) ? (g + 2) : 79;
            const float* wn = wp + (size_t)gn * 5 * O_;
            #pragma unroll
            for (int j = 0; j < 5; ++j)
                wbA[j] = *reinterpret_cast<const f4*>(wn + (size_t)j * O_);
        }
        compute(wbB, g + 1);
    }

    // ---- per-row argmax over all 256 o (exact tie handling like s == s.max())
    #pragma unroll
    for (int r = 0; r < 16; ++r) {
        const int wo = wo0 + r;
        float v = fmaxf(fmaxf(acc[r][0], acc[r][1]), fmaxf(acc[r][2], acc[r][3]));
        #pragma unroll
        for (int off = 32; off >= 1; off >>= 1) v = fmaxf(v, __shfl_xor(v, off));
        if (wo < Wo_) {
            const int n = (b * Ho_ + ho) * Wo_ + wo;
            #pragma unroll
            for (int u = 0; u < 4; ++u) {
                if (acc[r][u] == v) {                     // winner (possibly tied)
                    const int o = txo + 64 * u;
                    int pos = atomicAdd(&count[o], 1);
                    if (pos < cap) { lw_n[o * cap + pos] = n; lw_s[o * cap + pos] = v; }
                }
            }
        }
    }

    // ---- y stores: fp32, each lane owns 16 consecutive wo -> float4 stores
    {
        const int nf4 = (wo0 == 48) ? 3 : 4;     // wo 48..59 -> only 3 float4s valid
        #pragma unroll
        for (int u = 0; u < 4; ++u) {
            const int o = txo + 64 * u;
            float* row = y + ((size_t)(b * O_ + o) * Ho_ + ho) * (size_t)Wo_ + wo0;
            #pragma unroll
            for (int q = 0; q < 4; ++q) {
                if (q < nf4) {
                    f4 v4 = { acc[q * 4 + 0][u], acc[q * 4 + 1][u],
                              acc[q * 4 + 2][u], acc[q * 4 + 3][u] };
                    *reinterpret_cast<f4*>(row + q * 4) = v4;
                }
            }
        }
    }
}

// ---------------- phase 2a: per-slice partial sums (4 slices per o) ----------------
__global__ void delta_part_kernel(const float* __restrict__ x,
                                  const int* __restrict__ count, const int* __restrict__ lw_n,
                                  const float* __restrict__ lw_s, float* __restrict__ partial,
                                  float* __restrict__ ssum_part, int cap) {
    const int o   = blockIdx.x >> 2;
    const int sl  = blockIdx.x & 3;
    const int tid = threadIdx.x;
    int cnt = count[o]; if (cnt > cap) cnt = cap;
    const int e0 = (cnt * sl) >> 2;
    const int e1 = (cnt * (sl + 1)) >> 2;

    const int d0 = tid;
    const int c0 = d0 / 25, r0 = d0 % 25, i0 = r0 / 5, j0 = r0 % 5;
    const bool has1 = (tid < Dd - 256);
    const int dd1 = has1 ? tid + 256 : 0;
    const int c1 = dd1 / 25, r1 = dd1 % 25, i1 = r1 / 5, j1 = r1 % 5;

    const int* ln = lw_n + (size_t)o * cap;
    const float* ls = lw_s + (size_t)o * cap;

    float acc0 = 0.f, acc1 = 0.f, ssum = 0.f;
    for (int e = e0; e < e1; ++e) {
        const int n = ln[e];
        const float s = ls[e];
        const int bb = n / 3600;
        const int rem = n - bb * 3600;
        const int hh = rem / 60;
        const int ww2 = rem - hh * 60;
        ssum += s;
        const float* xb = x + (size_t)bb * (C_ * Hh * Ww);
        acc0 += s * xb[(c0 * Hh + hh + i0) * Ww + ww2 + j0];
        if (has1) acc1 += s * xb[(c1 * Hh + hh + i1) * Ww + ww2 + j1];
    }
    float* pp = partial + ((size_t)o * 4 + sl) * Dd;
    pp[tid] = acc0;
    if (has1) pp[tid + 256] = acc1;
    if (tid == 0) ssum_part[o * 4 + sl] = ssum;
}

// ---------------- phase 2b: reduce partials, apply -ssum/N * w ----------------
__global__ void delta_reduce_kernel(const float* __restrict__ w, const float* __restrict__ partial,
                                    const float* __restrict__ ssum_part,
                                    float* __restrict__ dout) {
    const int o = blockIdx.x, tid = threadIdx.x;
    const float ssum = ssum_part[o * 4] + ssum_part[o * 4 + 1]
                     + ssum_part[o * 4 + 2] + ssum_part[o * 4 + 3];
    const float invN = 1.0f / (float)Nn;
    const float* pp = partial + (size_t)o * 4 * Dd;
    float a0 = pp[tid] + pp[Dd + tid] + pp[2 * Dd + tid] + pp[3 * Dd + tid];
    dout[NY + (size_t)o * Dd + tid] = a0 * invN - ssum * invN * w[o * Dd + tid];
    if (tid < Dd - 256) {
        const int t2 = tid + 256;
        float a1 = pp[t2] + pp[Dd + t2] + pp[2 * Dd + t2] + pp[3 * Dd + t2];
        dout[NY + (size_t)o * Dd + t2] = a1 * invN - ssum * invN * w[o * Dd + t2];
    }
}

extern "C" void kernel_launch(void* const* d_in, const int* in_sizes, int n_in,
                              void* d_out, int out_size, void* d_ws, size_t ws_size,
                              hipStream_t stream) {
    (void)in_sizes; (void)n_in; (void)out_size;
    const float* x = (const float*)d_in[0];
    const float* w = (const float*)d_in[1];
    float* out = (float*)d_out;

    char* ws = (char*)d_ws;
    int*   count     = (int*)ws;                                   // 1,024 B
    float* wT4       = (float*)(ws + 1024);                        // 409,600 B
    float* partial   = (float*)(ws + 410624);                      // 1,638,400 B
    float* ssum_part = (float*)(ws + 410624 + 1638400);            // 4,096 B
    const size_t base = 410624 + 1638400 + 4096;                   // 2,053,120 B

    // size winner lists from the actual workspace; never write beyond it
    size_t avail = (ws_size > base) ? (ws_size - base) : 0;
    long long cap_ll = (long long)(avail / ((size_t)O_ * 8));
    int cap = (int)(cap_ll > 4096 ? 4096 : (cap_ll < 1 ? 1 : cap_ll));

    int*   lw_n = (int*)(ws + base);
    float* lw_s = (float*)(ws + base + (size_t)O_ * cap * 4);

    prep_kernel<<<dim3(Dd), dim3(O_), 0, stream>>>(w, wT4, count);
    conv_argmax_kernel<<<dim3(B_ * Ho_), dim3(256), 0, stream>>>(x, wT4, out, count, lw_n, lw_s, cap);
    delta_part_kernel<<<dim3(O_ * 4), dim3(256), 0, stream>>>(x, count, lw_n, lw_s, partial, ssum_part, cap);
    delta_reduce_kernel<<<dim3(O_), dim3(256), 0, stream>>>(w, partial, ssum_part, out);
}

// Round 7
// 373.929 us; speedup vs baseline: 2.5447x; 1.0073x over previous
//
#include <hip/hip_runtime.h>
#include <hip/hip_bf16.h>

// Problem dims
#define B_  32
#define C_  16
#define Hh  64
#define Ww  64
#define O_  256
#define Kk  5
#define Ho_ 60
#define Wo_ 60
#define Dd  400                 // C*K*K
#define Nn  (B_*Ho_*Wo_)        // 115200
#define NY  ((size_t)B_*O_*Ho_*Wo_)  // 29491200
#define KP  416                 // K padded to 13 chunks of 32
#define ACAP 16384              // ambiguous-row list capacity
#define TAU 3.0e-3f             // top-2 gap threshold for exact re-resolve

typedef float f4 __attribute__((ext_vector_type(4)));
typedef float f32x4 __attribute__((ext_vector_type(4)));
typedef unsigned int u32x2 __attribute__((ext_vector_type(2)));
typedef unsigned int u32x4 __attribute__((ext_vector_type(4)));
typedef __bf16 bf16x8 __attribute__((ext_vector_type(8)));

static __device__ __forceinline__ void bf16split(float v, unsigned short& h, unsigned short& l) {
    __hip_bfloat16 bh = __float2bfloat16(v);
    float vh = __bfloat162float(bh);
    __hip_bfloat16 bl = __float2bfloat16(v - vh);
    h = __builtin_bit_cast(unsigned short, bh);
    l = __builtin_bit_cast(unsigned short, bl);
}

// ---------------- prep: w [O][400] -> bf16 hi/lo planes [O][416]; zero counters ----------
__global__ void prep_kernel(const float* __restrict__ w, unsigned short* __restrict__ wbh,
                            unsigned short* __restrict__ wbl, int* __restrict__ count,
                            int* __restrict__ acnt) {
    const int o = blockIdx.x, t = threadIdx.x;
    for (int k = t; k < KP; k += 256) {
        float v = (k < Dd) ? w[o * Dd + k] : 0.f;
        unsigned short h, l; bf16split(v, h, l);
        wbh[o * KP + k] = h; wbl[o * KP + k] = l;
    }
    if (o == 0) { count[t] = 0; if (t == 0) *acnt = 0; }
}

// ---------------- phase 1: bf16x3 MFMA conv + top2 argmax + winner/ambig append ----------
// grid = 1920 (b,ho); 256 thr = 4 waves. Wave w: o in [64w, 64w+64). Block: p=wo in [0,64).
// MFMA 16x16x32: A lane(16q+r): m=r, k=8q+j. B lane(16q+r): k=8q+j, n=r.
// D lane(16q+r) reg i: row m=4q+i, col n=r.  (k-order robust: A,B share the (q,slot) map.)
__launch_bounds__(256, 3)
__global__ void conv_mfma_kernel(const float* __restrict__ x, const unsigned short* __restrict__ wbh,
                                 const unsigned short* __restrict__ wbl, float* __restrict__ y,
                                 int* __restrict__ count, int* __restrict__ lw_n,
                                 float* __restrict__ lw_s, int* __restrict__ acnt,
                                 int* __restrict__ ambig, int cap) {
    __shared__ unsigned short xsh[85 * 72];   // hi plane: rows g=0..79 real, 80..84 zero
    __shared__ unsigned short xsl[85 * 72];   // lo plane
    __shared__ float wm1[4][64], wm2[4][64];
    __shared__ float rowM1[64];

    const int tid = threadIdx.x;
    const int L = tid & 63, w = tid >> 6;
    const int q = L >> 4, r = L & 15;
    const int b = blockIdx.x / Ho_, ho = blockIdx.x % Ho_;

    // ---- stage x patch, converting fp32 -> bf16 hi/lo in-flight
    {
        const float* xb = x + (size_t)b * (C_ * Hh * Ww);
        #pragma unroll
        for (int s = 0; s < 5; ++s) {
            int idx = tid + s * 256;          // 0..1279
            int row = idx >> 4, col4 = idx & 15;
            int c = row / 5, i = row - c * 5;
            f4 v = *reinterpret_cast<const f4*>(xb + (c * Hh + ho + i) * Ww + col4 * 4);
            unsigned short h0, h1, h2, h3, l0, l1, l2, l3;
            bf16split(v.x, h0, l0); bf16split(v.y, h1, l1);
            bf16split(v.z, h2, l2); bf16split(v.w, h3, l3);
            u32x2 ph = { (unsigned)h0 | ((unsigned)h1 << 16), (unsigned)h2 | ((unsigned)h3 << 16) };
            u32x2 pl = { (unsigned)l0 | ((unsigned)l1 << 16), (unsigned)l2 | ((unsigned)l3 << 16) };
            *reinterpret_cast<u32x2*>(&xsh[row * 72 + col4 * 4]) = ph;
            *reinterpret_cast<u32x2*>(&xsl[row * 72 + col4 * 4]) = pl;
        }
        for (int idx = tid; idx < 5 * 72; idx += 256) { xsh[80 * 72 + idx] = 0; xsl[80 * 72 + idx] = 0; }
        for (int idx = tid; idx < 80 * 8; idx += 256) {
            int rr = idx >> 3, cc = 64 + (idx & 7);
            xsh[rr * 72 + cc] = 0; xsl[rr * 72 + cc] = 0;
        }
    }

    f32x4 acc[4][4];
    #pragma unroll
    for (int pt = 0; pt < 4; ++pt)
        #pragma unroll
        for (int t = 0; t < 4; ++t) { acc[pt][t].x = 0.f; acc[pt][t].y = 0.f; acc[pt][t].z = 0.f; acc[pt][t].w = 0.f; }

    __syncthreads();

    const unsigned short* wbh_lane = wbh + (size_t)(64 * w + r) * KP;
    const unsigned short* wbl_lane = wbl + (size_t)(64 * w + r) * KP;

    #pragma unroll 1
    for (int s = 0; s < 13; ++s) {
        const int koff = 32 * s + 8 * q;
        // B fragments: hi+lo for 4 o-tiles, 16B per-lane loads (L2-resident)
        u32x4 BH[4], BL[4];
        #pragma unroll
        for (int t = 0; t < 4; ++t) {
            BH[t] = *reinterpret_cast<const u32x4*>(wbh_lane + t * 16 * KP + koff);
            BL[t] = *reinterpret_cast<const u32x4*>(wbl_lane + t * 16 * KP + koff);
        }
        // A element addresses (pt=0); pt adds +16 u16 (imm offset)
        int aaddr[8];
        #pragma unroll
        for (int j = 0; j < 8; ++j) {
            int k = koff + j;
            int g = (k * 52429) >> 18;        // k/5 exact for k<13107
            int jc = k - g * 5;
            aaddr[j] = g * 72 + r + jc;
        }
        #pragma unroll
        for (int pt = 0; pt < 4; ++pt) {
            const int po = 16 * pt;
            unsigned short h0 = xsh[aaddr[0]+po], h1 = xsh[aaddr[1]+po], h2 = xsh[aaddr[2]+po], h3 = xsh[aaddr[3]+po];
            unsigned short h4 = xsh[aaddr[4]+po], h5 = xsh[aaddr[5]+po], h6 = xsh[aaddr[6]+po], h7 = xsh[aaddr[7]+po];
            unsigned short l0 = xsl[aaddr[0]+po], l1 = xsl[aaddr[1]+po], l2 = xsl[aaddr[2]+po], l3 = xsl[aaddr[3]+po];
            unsigned short l4 = xsl[aaddr[4]+po], l5 = xsl[aaddr[5]+po], l6 = xsl[aaddr[6]+po], l7 = xsl[aaddr[7]+po];
            u32x4 ah = { (unsigned)h0 | ((unsigned)h1 << 16), (unsigned)h2 | ((unsigned)h3 << 16),
                         (unsigned)h4 | ((unsigned)h5 << 16), (unsigned)h6 | ((unsigned)h7 << 16) };
            u32x4 al = { (unsigned)l0 | ((unsigned)l1 << 16), (unsigned)l2 | ((unsigned)l3 << 16),
                         (unsigned)l4 | ((unsigned)l5 << 16), (unsigned)l6 | ((unsigned)l7 << 16) };
            bf16x8 Ah = __builtin_bit_cast(bf16x8, ah);
            bf16x8 Al = __builtin_bit_cast(bf16x8, al);
            #pragma unroll
            for (int t = 0; t < 4; ++t) {
                bf16x8 Bh = __builtin_bit_cast(bf16x8, BH[t]);
                bf16x8 Bl = __builtin_bit_cast(bf16x8, BL[t]);
                acc[pt][t] = __builtin_amdgcn_mfma_f32_16x16x32_bf16(Ah, Bh, acc[pt][t], 0, 0, 0);
                acc[pt][t] = __builtin_amdgcn_mfma_f32_16x16x32_bf16(Ah, Bl, acc[pt][t], 0, 0, 0);
                acc[pt][t] = __builtin_amdgcn_mfma_f32_16x16x32_bf16(Al, Bh, acc[pt][t], 0, 0, 0);
            }
        }
    }

    // ---- per-row top-2 (wave-local over 64 o's, then cross-wave via LDS)
    #pragma unroll
    for (int pt = 0; pt < 4; ++pt) {
        #pragma unroll
        for (int i = 0; i < 4; ++i) {
            float a0 = acc[pt][0][i], a1 = acc[pt][1][i], a2 = acc[pt][2][i], a3 = acc[pt][3][i];
            float m1 = fmaxf(a0, a1), m2 = fminf(a0, a1);
            m2 = fmaxf(m2, fminf(m1, a2)); m1 = fmaxf(m1, a2);
            m2 = fmaxf(m2, fminf(m1, a3)); m1 = fmaxf(m1, a3);
            #pragma unroll
            for (int off = 1; off <= 8; off <<= 1) {
                float o1 = __shfl_xor(m1, off), o2 = __shfl_xor(m2, off);
                m2 = fmaxf(fminf(m1, o1), fmaxf(m2, o2));
                m1 = fmaxf(m1, o1);
            }
            if (r == 0) { int p = 16 * pt + 4 * q + i; wm1[w][p] = m1; wm2[w][p] = m2; }
        }
    }
    __syncthreads();
    if (tid < 64) {
        const int p = tid;
        float M1 = wm1[0][p], M2 = wm2[0][p];
        #pragma unroll
        for (int wv = 1; wv < 4; ++wv) {
            float c1 = wm1[wv][p], c2 = wm2[wv][p];
            M2 = fmaxf(fminf(M1, c1), fmaxf(M2, c2));
            M1 = fmaxf(M1, c1);
        }
        bool amb = (M1 - M2) < TAU;
        if (amb && p < Wo_) {
            int n = (b * Ho_ + ho) * Wo_ + p;
            int pos = atomicAdd(acnt, 1);
            if (pos < ACAP) ambig[pos] = n;
        }
        rowM1[p] = amb ? __builtin_inff() : M1;   // INF suppresses appends for ambiguous rows
    }
    __syncthreads();

    // ---- winner appends (exact equality vs block max; ties append all, like s==s.max())
    #pragma unroll
    for (int pt = 0; pt < 4; ++pt) {
        #pragma unroll
        for (int i = 0; i < 4; ++i) {
            const int p = 16 * pt + 4 * q + i;
            const float M = rowM1[p];
            if (p < Wo_) {
                const int n = (b * Ho_ + ho) * Wo_ + p;
                #pragma unroll
                for (int t = 0; t < 4; ++t) {
                    float v = acc[pt][t][i];
                    if (v == M) {
                        int o = 64 * w + 16 * t + r;
                        int pos = atomicAdd(&count[o], 1);
                        if (pos < cap) { lw_n[o * cap + pos] = n; lw_s[o * cap + pos] = v; }
                    }
                }
            }
        }
    }

    // ---- y stores: acc reg vector = 4 consecutive wo for one o -> dwordx4
    #pragma unroll
    for (int pt = 0; pt < 4; ++pt) {
        const int wo = 16 * pt + 4 * q;
        if (wo < Wo_) {                       // skips (pt=3,q=3) = wo 60..63
            #pragma unroll
            for (int t = 0; t < 4; ++t) {
                const int o = 64 * w + 16 * t + r;
                f4 v = { acc[pt][t].x, acc[pt][t].y, acc[pt][t].z, acc[pt][t].w };
                *reinterpret_cast<f4*>(y + ((size_t)(b * O_ + o) * Ho_ + ho) * (size_t)Wo_ + wo) = v;
            }
        }
    }
}

// ---------------- fallback: exact fp32 re-resolve of ambiguous rows ----------------
__global__ void fallback_kernel(const float* __restrict__ x, const float* __restrict__ w,
                                const int* __restrict__ acnt, const int* __restrict__ ambig,
                                int* __restrict__ count, int* __restrict__ lw_n,
                                float* __restrict__ lw_s, int cap) {
    __shared__ float xrow[Dd];
    __shared__ float red[256];
    int cnt = *acnt; if (cnt > ACAP) cnt = ACAP;
    for (int idx = blockIdx.x; idx < cnt; idx += gridDim.x) {
        const int n = ambig[idx];
        const int bb = n / 3600, rem = n % 3600, hh = rem / 60, ww2 = rem % 60;
        for (int k = threadIdx.x; k < Dd; k += 256) {
            int c = k / 25, rr = k % 25, i = rr / 5, j = rr % 5;
            xrow[k] = x[(((size_t)bb * C_ + c) * Hh + hh + i) * Ww + ww2 + j];
        }
        __syncthreads();
        const int o = threadIdx.x;
        const float* wr = w + (size_t)o * Dd;
        float s = 0.f;
        #pragma unroll 4
        for (int k = 0; k < Dd; ++k) s = fmaf(xrow[k], wr[k], s);
        red[o] = s;
        __syncthreads();
        #pragma unroll
        for (int st = 128; st >= 1; st >>= 1) {
            if (o < st) red[o] = fmaxf(red[o], red[o + st]);
            __syncthreads();
        }
        const float mx = red[0];
        if (s == mx) {
            int pos = atomicAdd(&count[o], 1);
            if (pos < cap) { lw_n[o * cap + pos] = n; lw_s[o * cap + pos] = s; }
        }
        __syncthreads();
    }
}

// ---------------- phase 2a: per-slice partial sums (4 slices per o) ----------------
__global__ void delta_part_kernel(const float* __restrict__ x,
                                  const int* __restrict__ count, const int* __restrict__ lw_n,
                                  const float* __restrict__ lw_s, float* __restrict__ partial,
                                  float* __restrict__ ssum_part, int cap) {
    const int o   = blockIdx.x >> 2;
    const int sl  = blockIdx.x & 3;
    const int tid = threadIdx.x;
    int cnt = count[o]; if (cnt > cap) cnt = cap;
    const int e0 = (cnt * sl) >> 2;
    const int e1 = (cnt * (sl + 1)) >> 2;

    const int d0 = tid;
    const int c0 = d0 / 25, r0 = d0 % 25, i0 = r0 / 5, j0 = r0 % 5;
    const bool has1 = (tid < Dd - 256);
    const int dd1 = has1 ? tid + 256 : 0;
    const int c1 = dd1 / 25, r1 = dd1 % 25, i1 = r1 / 5, j1 = r1 % 5;

    const int* ln = lw_n + (size_t)o * cap;
    const float* ls = lw_s + (size_t)o * cap;

    float acc0 = 0.f, acc1 = 0.f, ssum = 0.f;
    for (int e = e0; e < e1; ++e) {
        const int n = ln[e];
        const float s = ls[e];
        const int bb = n / 3600;
        const int rem = n - bb * 3600;
        const int hh = rem / 60;
        const int ww2 = rem - hh * 60;
        ssum += s;
        const float* xb = x + (size_t)bb * (C_ * Hh * Ww);
        acc0 += s * xb[(c0 * Hh + hh + i0) * Ww + ww2 + j0];
        if (has1) acc1 += s * xb[(c1 * Hh + hh + i1) * Ww + ww2 + j1];
    }
    float* pp = partial + ((size_t)o * 4 + sl) * Dd;
    pp[tid] = acc0;
    if (has1) pp[tid + 256] = acc1;
    if (tid == 0) ssum_part[o * 4 + sl] = ssum;
}

// ---------------- phase 2b: reduce partials, apply -ssum/N * w ----------------
__global__ void delta_reduce_kernel(const float* __restrict__ w, const float* __restrict__ partial,
                                    const float* __restrict__ ssum_part,
                                    float* __restrict__ dout) {
    const int o = blockIdx.x, tid = threadIdx.x;
    const float ssum = ssum_part[o * 4] + ssum_part[o * 4 + 1]
                     + ssum_part[o * 4 + 2] + ssum_part[o * 4 + 3];
    const float invN = 1.0f / (float)Nn;
    const float* pp = partial + (size_t)o * 4 * Dd;
    float a0 = pp[tid] + pp[Dd + tid] + pp[2 * Dd + tid] + pp[3 * Dd + tid];
    dout[NY + (size_t)o * Dd + tid] = a0 * invN - ssum * invN * w[o * Dd + tid];
    if (tid < Dd - 256) {
        const int t2 = tid + 256;
        float a1 = pp[t2] + pp[Dd + t2] + pp[2 * Dd + t2] + pp[3 * Dd + t2];
        dout[NY + (size_t)o * Dd + t2] = a1 * invN - ssum * invN * w[o * Dd + t2];
    }
}

extern "C" void kernel_launch(void* const* d_in, const int* in_sizes, int n_in,
                              void* d_out, int out_size, void* d_ws, size_t ws_size,
                              hipStream_t stream) {
    (void)in_sizes; (void)n_in; (void)out_size;
    const float* x = (const float*)d_in[0];
    const float* w = (const float*)d_in[1];
    float* out = (float*)d_out;

    char* ws = (char*)d_ws;
    int*            count     = (int*)ws;                          // @0       (1,024 B)
    int*            acnt      = (int*)(ws + 1024);                 // @1024    (64 B)
    unsigned short* wbh       = (unsigned short*)(ws + 1088);      // @1088    (212,992 B)
    unsigned short* wbl       = (unsigned short*)(ws + 214080);    //          (212,992 B)
    int*            ambig     = (int*)(ws + 427072);               //          (65,536 B)
    float*          partial   = (float*)(ws + 492608);             //          (1,638,400 B)
    float*          ssum_part = (float*)(ws + 2131008);            //          (4,096 B)
    const size_t base = 2135104;

    size_t avail = (ws_size > base) ? (ws_size - base) : 0;
    long long cap_ll = (long long)(avail / ((size_t)O_ * 8));
    int cap = (int)(cap_ll > 4096 ? 4096 : (cap_ll < 1 ? 1 : cap_ll));

    int*   lw_n = (int*)(ws + base);
    float* lw_s = (float*)(ws + base + (size_t)O_ * cap * 4);

    prep_kernel<<<dim3(O_), dim3(256), 0, stream>>>(w, wbh, wbl, count, acnt);
    conv_mfma_kernel<<<dim3(B_ * Ho_), dim3(256), 0, stream>>>(x, wbh, wbl, out, count, lw_n, lw_s,
                                                               acnt, ambig, cap);
    fallback_kernel<<<dim3(256), dim3(256), 0, stream>>>(x, w, acnt, ambig, count, lw_n, lw_s, cap);
    delta_part_kernel<<<dim3(O_ * 4), dim3(256), 0, stream>>>(x, count, lw_n, lw_s, partial, ssum_part, cap);
    delta_reduce_kernel<<<dim3(O_), dim3(256), 0, stream>>>(w, partial, ssum_part, out);
}

// Round 8
// 252.257 us; speedup vs baseline: 3.7721x; 1.4823x over previous
//
#include <hip/hip_runtime.h>
#include <hip/hip_bf16.h>

// Problem dims
#define B_  32
#define C_  16
#define Hh  64
#define Ww  64
#define O_  256
#define Kk  5
#define Ho_ 60
#define Wo_ 60
#define Dd  400                 // C*K*K
#define Nn  (B_*Ho_*Wo_)        // 115200
#define NY  ((size_t)B_*O_*Ho_*Wo_)  // 29491200
#define ACAP 16384              // ambiguous-row list capacity
#define TAU 2.5e-4f             // top-2 gap threshold (bf16x3 max err ~1e-5, 25x margin)

typedef float f4 __attribute__((ext_vector_type(4)));
typedef float f32x4 __attribute__((ext_vector_type(4)));
typedef unsigned int u32x4 __attribute__((ext_vector_type(4)));
typedef __bf16 bf16x8 __attribute__((ext_vector_type(8)));

static __device__ __forceinline__ void bf16split(float v, unsigned short& h, unsigned short& l) {
    __hip_bfloat16 bh = __float2bfloat16(v);
    float vh = __bfloat162float(bh);
    __hip_bfloat16 bl = __float2bfloat16(v - vh);
    h = __builtin_bit_cast(unsigned short, bh);
    l = __builtin_bit_cast(unsigned short, bl);
}

// ---- prep: pack w into per-tap coalesced MFMA-B layout, bf16 hi/lo planes ----
// wpk[(jc*3+s)][wv][t][q][r][j] (u16): o = 64wv+16t+r, k-slot = 8q+j -> g = 32s+8q+j,
// value = w[o][g*5 + jc] (g<80 else 0). Lane (q,r) reads its 16B at base + L*16.
__global__ void prep_kernel(const float* __restrict__ w, unsigned short* __restrict__ wpkH,
                            unsigned short* __restrict__ wpkL, int* __restrict__ count,
                            int* __restrict__ acnt) {
    const int bi = blockIdx.x;          // 0..59
    const int wv = bi & 3;
    const int u  = bi >> 2;             // 0..14 = jc*3 + s
    const int jc = u / 3, s = u - (u / 3) * 3;
    const int tid = threadIdx.x;
    const int t = tid >> 6, q = (tid >> 4) & 3, r = tid & 15;
    const int o = 64 * wv + 16 * t + r;
    unsigned short h[8], l[8];
    #pragma unroll
    for (int j = 0; j < 8; ++j) {
        int gk = 32 * s + 8 * q + j;
        float v = (gk < 80) ? w[o * Dd + gk * 5 + jc] : 0.f;
        bf16split(v, h[j], l[j]);
    }
    const size_t base = (size_t)u * 8192 + wv * 2048 + t * 512 + q * 128 + r * 8;  // u16 units
    u32x4 ph = { (unsigned)h[0] | ((unsigned)h[1] << 16), (unsigned)h[2] | ((unsigned)h[3] << 16),
                 (unsigned)h[4] | ((unsigned)h[5] << 16), (unsigned)h[6] | ((unsigned)h[7] << 16) };
    u32x4 pl = { (unsigned)l[0] | ((unsigned)l[1] << 16), (unsigned)l[2] | ((unsigned)l[3] << 16),
                 (unsigned)l[4] | ((unsigned)l[5] << 16), (unsigned)l[6] | ((unsigned)l[7] << 16) };
    *reinterpret_cast<u32x4*>(wpkH + base) = ph;
    *reinterpret_cast<u32x4*>(wpkL + base) = pl;
    if (bi == 0) { count[tid] = 0; if (tid == 0) *acnt = 0; }
}

// ---- phase 1: tap-split bf16x3 MFMA conv + top2 argmax + winner/ambig append ----
// grid 1920 (b,ho); 4 waves; wave wv: o in [64wv,64wv+64); block covers wo 0..63 (4 pt tiles).
// A fragment: one ds_read_b128 per plane from transposed LDS xT[v][g] (208B row stride).
__launch_bounds__(256, 3)
__global__ void conv_mfma_kernel(const float* __restrict__ x, const unsigned short* __restrict__ wpkH,
                                 const unsigned short* __restrict__ wpkL, float* __restrict__ y,
                                 int* __restrict__ count, int* __restrict__ lw_n,
                                 float* __restrict__ lw_s, int* __restrict__ acnt,
                                 int* __restrict__ ambig, int cap) {
    __shared__ __align__(16) unsigned short xT[2 * 7072];   // [plane][v 0..67][g 0..103]
    __shared__ float wm1[4][64], wm2[4][64];
    __shared__ float rowM1[64];

    const int tid = threadIdx.x;
    const int L = tid & 63, wv = tid >> 6;
    const int q = L >> 4, r = L & 15;
    const int b = blockIdx.x / Ho_, ho = blockIdx.x % Ho_;

    // ---- zero pad regions (disjoint from staged region): cols 80..95 all rows; rows 64..67 cols 0..79
    {
        u32x4 z = { 0, 0, 0, 0 };
        for (int id = tid; id < 272; id += 256) {
            int plane = id & 1, rem = id >> 1, row = rem >> 1, half = rem & 1;
            *reinterpret_cast<u32x4*>(&xT[plane * 7072 + row * 104 + 80 + half * 8]) = z;
        }
        if (tid < 80) {
            int plane = tid / 40, rem = tid % 40, row = 64 + rem / 10, blk = rem % 10;
            *reinterpret_cast<u32x4*>(&xT[plane * 7072 + row * 104 + blk * 8]) = z;
        }
    }

    // ---- stage x patch transposed: xT[plane][v][g] = split(x[b][c][ho+i][v]), g = c*5+i
    {
        const float* xb = x + (size_t)b * (C_ * Hh * Ww);
        #pragma unroll
        for (int sq = 0; sq < 5; ++sq) {
            int idx = tid + sq * 256;        // 0..1279
            int g = idx >> 4, col4 = idx & 15;
            int c = g / 5, i = g - c * 5;
            f4 v = *reinterpret_cast<const f4*>(xb + (c * Hh + ho + i) * Ww + col4 * 4);
            unsigned short hh[4], ll[4];
            bf16split(v.x, hh[0], ll[0]); bf16split(v.y, hh[1], ll[1]);
            bf16split(v.z, hh[2], ll[2]); bf16split(v.w, hh[3], ll[3]);
            #pragma unroll
            for (int e = 0; e < 4; ++e) {
                int vv = col4 * 4 + e;
                xT[vv * 104 + g] = hh[e];
                xT[7072 + vv * 104 + g] = ll[e];
            }
        }
    }

    f32x4 acc[4][4];
    #pragma unroll
    for (int pt = 0; pt < 4; ++pt)
        #pragma unroll
        for (int t = 0; t < 4; ++t) { acc[pt][t].x = 0.f; acc[pt][t].y = 0.f; acc[pt][t].z = 0.f; acc[pt][t].w = 0.f; }

    __syncthreads();

    const unsigned short* bh0 = wpkH + wv * 2048 + (size_t)L * 8;
    const unsigned short* bl0 = wpkL + wv * 2048 + (size_t)L * 8;
    const int abase = r * 104 + q * 8;       // u16 units; + jc*104 + s*32 + pt*1664 (+7072 lo plane)

    #pragma unroll 1
    for (int jc = 0; jc < 5; ++jc) {
        #pragma unroll 1
        for (int s = 0; s < 3; ++s) {
            const unsigned short* bhp = bh0 + (jc * 3 + s) * 8192;
            const unsigned short* blp = bl0 + (jc * 3 + s) * 8192;
            u32x4 BH[4], BL[4];
            #pragma unroll
            for (int t = 0; t < 4; ++t) {
                BH[t] = *reinterpret_cast<const u32x4*>(bhp + t * 512);
                BL[t] = *reinterpret_cast<const u32x4*>(blp + t * 512);
            }
            const int ao = abase + jc * 104 + s * 32;
            #pragma unroll
            for (int pt = 0; pt < 4; ++pt) {
                u32x4 AHu = *reinterpret_cast<const u32x4*>(&xT[ao + pt * 1664]);
                u32x4 ALu = *reinterpret_cast<const u32x4*>(&xT[7072 + ao + pt * 1664]);
                bf16x8 Ah = __builtin_bit_cast(bf16x8, AHu);
                bf16x8 Al = __builtin_bit_cast(bf16x8, ALu);
                #pragma unroll
                for (int t = 0; t < 4; ++t) {
                    bf16x8 Bh = __builtin_bit_cast(bf16x8, BH[t]);
                    bf16x8 Bl = __builtin_bit_cast(bf16x8, BL[t]);
                    acc[pt][t] = __builtin_amdgcn_mfma_f32_16x16x32_bf16(Ah, Bh, acc[pt][t], 0, 0, 0);
                    acc[pt][t] = __builtin_amdgcn_mfma_f32_16x16x32_bf16(Ah, Bl, acc[pt][t], 0, 0, 0);
                    acc[pt][t] = __builtin_amdgcn_mfma_f32_16x16x32_bf16(Al, Bh, acc[pt][t], 0, 0, 0);
                }
            }
        }
    }

    // ---- per-row top-2 (wave-local over 64 o's, then cross-wave via LDS)
    #pragma unroll
    for (int pt = 0; pt < 4; ++pt) {
        #pragma unroll
        for (int i = 0; i < 4; ++i) {
            float a0 = acc[pt][0][i], a1 = acc[pt][1][i], a2 = acc[pt][2][i], a3 = acc[pt][3][i];
            float m1 = fmaxf(a0, a1), m2 = fminf(a0, a1);
            m2 = fmaxf(m2, fminf(m1, a2)); m1 = fmaxf(m1, a2);
            m2 = fmaxf(m2, fminf(m1, a3)); m1 = fmaxf(m1, a3);
            #pragma unroll
            for (int off = 1; off <= 8; off <<= 1) {
                float o1 = __shfl_xor(m1, off), o2 = __shfl_xor(m2, off);
                m2 = fmaxf(fminf(m1, o1), fmaxf(m2, o2));
                m1 = fmaxf(m1, o1);
            }
            if (r == 0) { int p = 16 * pt + 4 * q + i; wm1[wv][p] = m1; wm2[wv][p] = m2; }
        }
    }
    __syncthreads();
    if (tid < 64) {
        const int p = tid;
        float M1 = wm1[0][p], M2 = wm2[0][p];
        #pragma unroll
        for (int w2 = 1; w2 < 4; ++w2) {
            float c1 = wm1[w2][p], c2 = wm2[w2][p];
            M2 = fmaxf(fminf(M1, c1), fmaxf(M2, c2));
            M1 = fmaxf(M1, c1);
        }
        bool amb = (M1 - M2) < TAU;
        if (amb && p < Wo_) {
            int n = (b * Ho_ + ho) * Wo_ + p;
            int pos = atomicAdd(acnt, 1);
            if (pos < ACAP) ambig[pos] = n;
        }
        rowM1[p] = amb ? __builtin_inff() : M1;   // INF suppresses appends for ambiguous rows
    }
    __syncthreads();

    // ---- winner appends (exact equality vs block max; ties append all, like s==s.max())
    #pragma unroll
    for (int pt = 0; pt < 4; ++pt) {
        #pragma unroll
        for (int i = 0; i < 4; ++i) {
            const int p = 16 * pt + 4 * q + i;
            const float M = rowM1[p];
            if (p < Wo_) {
                const int n = (b * Ho_ + ho) * Wo_ + p;
                #pragma unroll
                for (int t = 0; t < 4; ++t) {
                    float v = acc[pt][t][i];
                    if (v == M) {
                        int o = 64 * wv + 16 * t + r;
                        int pos = atomicAdd(&count[o], 1);
                        if (pos < cap) { lw_n[o * cap + pos] = n; lw_s[o * cap + pos] = v; }
                    }
                }
            }
        }
    }

    // ---- y stores: acc reg vector = 4 consecutive wo for one o -> dwordx4
    #pragma unroll
    for (int pt = 0; pt < 4; ++pt) {
        const int wo = 16 * pt + 4 * q;
        if (wo < Wo_) {                       // skips (pt=3,q=3) = wo 60..63
            #pragma unroll
            for (int t = 0; t < 4; ++t) {
                const int o = 64 * wv + 16 * t + r;
                f4 v = { acc[pt][t].x, acc[pt][t].y, acc[pt][t].z, acc[pt][t].w };
                *reinterpret_cast<f4*>(y + ((size_t)(b * O_ + o) * Ho_ + ho) * (size_t)Wo_ + wo) = v;
            }
        }
    }
}

// ---- fallback: exact fp32 re-resolve of ambiguous rows ----
__global__ void fallback_kernel(const float* __restrict__ x, const float* __restrict__ w,
                                const int* __restrict__ acnt, const int* __restrict__ ambig,
                                int* __restrict__ count, int* __restrict__ lw_n,
                                float* __restrict__ lw_s, int cap) {
    __shared__ float xrow[Dd];
    __shared__ float red[256];
    int cnt = *acnt; if (cnt > ACAP) cnt = ACAP;
    for (int idx = blockIdx.x; idx < cnt; idx += gridDim.x) {
        const int n = ambig[idx];
        const int bb = n / 3600, rem = n % 3600, hh = rem / 60, ww2 = rem % 60;
        for (int k = threadIdx.x; k < Dd; k += 256) {
            int c = k / 25, rr = k % 25, i = rr / 5, j = rr % 5;
            xrow[k] = x[(((size_t)bb * C_ + c) * Hh + hh + i) * Ww + ww2 + j];
        }
        __syncthreads();
        const int o = threadIdx.x;
        const float* wr = w + (size_t)o * Dd;
        float s = 0.f;
        #pragma unroll 4
        for (int k = 0; k < Dd; ++k) s = fmaf(xrow[k], wr[k], s);
        red[o] = s;
        __syncthreads();
        #pragma unroll
        for (int st = 128; st >= 1; st >>= 1) {
            if (o < st) red[o] = fmaxf(red[o], red[o + st]);
            __syncthreads();
        }
        const float mx = red[0];
        if (s == mx) {
            int pos = atomicAdd(&count[o], 1);
            if (pos < cap) { lw_n[o * cap + pos] = n; lw_s[o * cap + pos] = s; }
        }
        __syncthreads();
    }
}

// ---- phase 2a: per-slice partial sums (4 slices per o) ----
__global__ void delta_part_kernel(const float* __restrict__ x,
                                  const int* __restrict__ count, const int* __restrict__ lw_n,
                                  const float* __restrict__ lw_s, float* __restrict__ partial,
                                  float* __restrict__ ssum_part, int cap) {
    const int o   = blockIdx.x >> 2;
    const int sl  = blockIdx.x & 3;
    const int tid = threadIdx.x;
    int cnt = count[o]; if (cnt > cap) cnt = cap;
    const int e0 = (cnt * sl) >> 2;
    const int e1 = (cnt * (sl + 1)) >> 2;

    const int d0 = tid;
    const int c0 = d0 / 25, r0 = d0 % 25, i0 = r0 / 5, j0 = r0 % 5;
    const bool has1 = (tid < Dd - 256);
    const int dd1 = has1 ? tid + 256 : 0;
    const int c1 = dd1 / 25, r1 = dd1 % 25, i1 = r1 / 5, j1 = r1 % 5;

    const int* ln = lw_n + (size_t)o * cap;
    const float* ls = lw_s + (size_t)o * cap;

    float acc0 = 0.f, acc1 = 0.f, ssum = 0.f;
    for (int e = e0; e < e1; ++e) {
        const int n = ln[e];
        const float s = ls[e];
        const int bb = n / 3600;
        const int rem = n - bb * 3600;
        const int hh = rem / 60;
        const int ww2 = rem - hh * 60;
        ssum += s;
        const float* xb = x + (size_t)bb * (C_ * Hh * Ww);
        acc0 += s * xb[(c0 * Hh + hh + i0) * Ww + ww2 + j0];
        if (has1) acc1 += s * xb[(c1 * Hh + hh + i1) * Ww + ww2 + j1];
    }
    float* pp = partial + ((size_t)o * 4 + sl) * Dd;
    pp[tid] = acc0;
    if (has1) pp[tid + 256] = acc1;
    if (tid == 0) ssum_part[o * 4 + sl] = ssum;
}

// ---- phase 2b: reduce partials, apply -ssum/N * w ----
__global__ void delta_reduce_kernel(const float* __restrict__ w, const float* __restrict__ partial,
                                    const float* __restrict__ ssum_part,
                                    float* __restrict__ dout) {
    const int o = blockIdx.x, tid = threadIdx.x;
    const float ssum = ssum_part[o * 4] + ssum_part[o * 4 + 1]
                     + ssum_part[o * 4 + 2] + ssum_part[o * 4 + 3];
    const float invN = 1.0f / (float)Nn;
    const float* pp = partial + (size_t)o * 4 * Dd;
    float a0 = pp[tid] + pp[Dd + tid] + pp[2 * Dd + tid] + pp[3 * Dd + tid];
    dout[NY + (size_t)o * Dd + tid] = a0 * invN - ssum * invN * w[o * Dd + tid];
    if (tid < Dd - 256) {
        const int t2 = tid + 256;
        float a1 = pp[t2] + pp[Dd + t2] + pp[2 * Dd + t2] + pp[3 * Dd + t2];
        dout[NY + (size_t)o * Dd + t2] = a1 * invN - ssum * invN * w[o * Dd + t2];
    }
}

extern "C" void kernel_launch(void* const* d_in, const int* in_sizes, int n_in,
                              void* d_out, int out_size, void* d_ws, size_t ws_size,
                              hipStream_t stream) {
    (void)in_sizes; (void)n_in; (void)out_size;
    const float* x = (const float*)d_in[0];
    const float* w = (const float*)d_in[1];
    float* out = (float*)d_out;

    char* ws = (char*)d_ws;
    int*            count     = (int*)ws;                          // @0         (1,024 B)
    int*            acnt      = (int*)(ws + 1024);                 // @1,024     (64 B)
    int*            ambig     = (int*)(ws + 1088);                 // @1,088     (65,536 B)
    unsigned short* wpkH      = (unsigned short*)(ws + 66624);     // @66,624    (245,760 B)
    unsigned short* wpkL      = (unsigned short*)(ws + 312384);    // @312,384   (245,760 B)
    float*          partial   = (float*)(ws + 558144);             // @558,144   (1,638,400 B)
    float*          ssum_part = (float*)(ws + 2196544);            // @2,196,544 (4,096 B)
    const size_t base = 2200640;

    size_t avail = (ws_size > base) ? (ws_size - base) : 0;
    long long cap_ll = (long long)(avail / ((size_t)O_ * 8));
    int cap = (int)(cap_ll > 4096 ? 4096 : (cap_ll < 1 ? 1 : cap_ll));

    int*   lw_n = (int*)(ws + base);
    float* lw_s = (float*)(ws + base + (size_t)O_ * cap * 4);

    prep_kernel<<<dim3(60), dim3(256), 0, stream>>>(w, wpkH, wpkL, count, acnt);
    conv_mfma_kernel<<<dim3(B_ * Ho_), dim3(256), 0, stream>>>(x, wpkH, wpkL, out, count, lw_n, lw_s,
                                                               acnt, ambig, cap);
    fallback_kernel<<<dim3(256), dim3(256), 0, stream>>>(x, w, acnt, ambig, count, lw_n, lw_s, cap);
    delta_part_kernel<<<dim3(O_ * 4), dim3(256), 0, stream>>>(x, count, lw_n, lw_s, partial, ssum_part, cap);
    delta_reduce_kernel<<<dim3(O_), dim3(256), 0, stream>>>(w, partial, ssum_part, out);
}